// Round 4
// baseline (504.482 us; speedup 1.0000x reference)
//
#include <hip/hip_runtime.h>

typedef unsigned int u32;
typedef unsigned short u16;

#define NN 8192
#define FIN 512
#define FOUT 128
#define NH 16
#define BK 64    // h GEMM K-slab (u16 cols)

typedef float f32x16 __attribute__((ext_vector_type(16)));
typedef __bf16 bf16x8 __attribute__((ext_vector_type(8)));

union PackAB { u32 u[4]; bf16x8 v; };

__device__ __forceinline__ u32 rne_hi(u32 u) {
  return u + (0x7FFFu + ((u >> 16) & 1u));  // RNE bf16 in high half
}
__device__ __forceinline__ u16 f32_to_bf16(float f) {
  return (u16)(rne_hi(__float_as_uint(f)) >> 16);
}

// ---------------- K0: WT = bf16(W^T) [128][512]; w1s = folded w1.
__global__ __launch_bounds__(256) void prep_kernel(
    const float* __restrict__ W, const float* __restrict__ w1,
    u16* __restrict__ WT, float* __restrict__ w1s) {
  int b = blockIdx.x, t = threadIdx.x;
  if (b < 256) {
    int o = b * 256 + t;
    int n = o >> 9, k = o & 511;
    WT[o] = f32_to_bf16(W[k * FOUT + n]);
  } else {
    for (int e = t; e < NH * FOUT; e += 256) {
      int k = e >> 7, f = e & 127;
      w1s[e] = w1[k * 256 + f] + w1[k * 256 + 128 + f];
    }
  }
}

// ---------------- K1: fused h = x@W (full K=512 per 32-row tile),
// then HTf frag-order write + attn-net -> qpart, all from LDS.
__global__ __launch_bounds__(256) void h_fused_kernel(
    const float* __restrict__ x, const u16* __restrict__ WT,
    const float* __restrict__ b1, const float* __restrict__ w21,
    const float* __restrict__ b21, const float* __restrict__ w22,
    const float* __restrict__ b22, const float* __restrict__ w1s,
    u16* __restrict__ HTf, float* __restrict__ qpart) {
  __shared__ union {
    struct { u16 aS[32 * BK]; u16 bS[128 * BK]; } g;  // 20.0 KB
    float hs[32][FOUT + 4];                            // 16.5 KB
  } S;
  __shared__ float w1l[NH][FOUT + 4];
  __shared__ float us[32][NH + 1];
  int t = threadIdx.x;
  int w = t >> 6, l = t & 63;
  int m = l & 31, kh = l >> 5;
  int i0 = blockIdx.x * 32;

  int arow = t >> 4, acol = (t & 15) * 4;
  int ac = (t & 15) >> 1, ah = t & 1;
  int aoff0 = arow * BK + ((ac ^ (arow & 7)) << 3) + ah * 4;
  int aoff1 = (arow + 16) * BK + ((ac ^ ((arow + 16) & 7)) << 3) + ah * 4;
  const float* ap0 = x + (size_t)(i0 + arow) * FIN + acol;
  const float* ap1 = ap0 + (size_t)16 * FIN;
  int hr = t >> 3, hc = t & 7;
  const u16* bp0 = WT + (size_t)hr * FIN + hc * 8;
  int boff[4];
#pragma unroll
  for (int p = 0; p < 4; ++p) {
    int r = hr + 32 * p;
    boff[p] = r * BK + ((hc ^ (r & 7)) << 3);
  }
  int aro = m * BK, am7 = m & 7;
  int nB = w * 32 + m;
  int bro = nB * BK, bm7 = nB & 7;

  // Preload the entire 32x512 x-panel: 16 float4/thread = one 64 KB burst.
  float4 xa[8], xb[8];
#pragma unroll
  for (int o = 0; o < 8; ++o) {
    xa[o] = *(const float4*)(ap0 + o * BK);
    xb[o] = *(const float4*)(ap1 + o * BK);
  }
  uint4 hC[4], hN[4];
#pragma unroll
  for (int j = 0; j < 4; ++j) hC[j] = *(const uint4*)(bp0 + (size_t)(32 * j) * FIN);
  bp0 += BK;

  f32x16 acc;
#pragma unroll
  for (int r = 0; r < 16; ++r) acc[r] = 0.0f;

#pragma unroll
  for (int o = 0; o < 8; ++o) {
    if (o) __syncthreads();
    uint2 w0, w1v;
    w0.x = (rne_hi(__float_as_uint(xa[o].y)) & 0xFFFF0000u) | (rne_hi(__float_as_uint(xa[o].x)) >> 16);
    w0.y = (rne_hi(__float_as_uint(xa[o].w)) & 0xFFFF0000u) | (rne_hi(__float_as_uint(xa[o].z)) >> 16);
    w1v.x = (rne_hi(__float_as_uint(xb[o].y)) & 0xFFFF0000u) | (rne_hi(__float_as_uint(xb[o].x)) >> 16);
    w1v.y = (rne_hi(__float_as_uint(xb[o].w)) & 0xFFFF0000u) | (rne_hi(__float_as_uint(xb[o].z)) >> 16);
    *(uint2*)&S.g.aS[aoff0] = w0;
    *(uint2*)&S.g.aS[aoff1] = w1v;
#pragma unroll
    for (int j = 0; j < 4; ++j) *(uint4*)&S.g.bS[boff[j]] = hC[j];
    __syncthreads();
    if (o + 1 < 8) {
#pragma unroll
      for (int j = 0; j < 4; ++j) hN[j] = *(const uint4*)(bp0 + (size_t)(32 * j) * FIN);
      bp0 += BK;
    }
#pragma unroll
    for (int s = 0; s < BK; s += 16) {
      int cA = (s >> 3) + kh;
      PackAB pa, pb;
      pa.v = *(const bf16x8*)&S.g.aS[aro + ((cA ^ am7) << 3)];
      pb.v = *(const bf16x8*)&S.g.bS[bro + ((cA ^ bm7) << 3)];
      acc = __builtin_amdgcn_mfma_f32_32x32x16_bf16(pa.v, pb.v, acc, 0, 0, 0);
    }
    if (o + 1 < 8) {
#pragma unroll
      for (int j = 0; j < 4; ++j) hC[j] = hN[j];
    }
  }
  __syncthreads();  // last MFMA reads of aS/bS done before hs overwrite
  {
    int col = w * 32 + m;
#pragma unroll
    for (int r = 0; r < 16; ++r) {
      int row = (r & 3) + 8 * (r >> 2) + 4 * kh;
      S.hs[row][col] = acc[r];
    }
  }
  for (int e = t; e < NH * FOUT; e += 256) w1l[e >> 7][e & 127] = w1s[e];
  __syncthreads();
  // HTf in MFMA B-fragment order: idx = ((k16*4 + n/32)*64 + (kh*32 + n%32))*8 + k%8
  {
    int n = t & 127, g2 = t >> 7;
#pragma unroll
    for (int gg = 0; gg < 2; ++gg) {
      int g = g2 + 2 * gg;
      int k16 = (i0 >> 4) + (g >> 1), khh = g & 1;
      u32 p[4];
#pragma unroll
      for (int j = 0; j < 4; ++j) {
        u16 lo = f32_to_bf16(S.hs[g * 8 + 2 * j][n]);
        u16 hi = f32_to_bf16(S.hs[g * 8 + 2 * j + 1][n]);
        p[j] = (u32)lo | ((u32)hi << 16);
      }
      uint4 st; st.x = p[0]; st.y = p[1]; st.z = p[2]; st.w = p[3];
      size_t off = ((size_t)(k16 * 4 + (n >> 5)) * 64 + khh * 32 + (n & 31)) * 8;
      *(uint4*)(HTf + off) = st;
    }
  }
  {
    int i = t >> 3, p = t & 7;
    float s0 = b1[p], s1 = b1[p + 8];
#pragma unroll 4
    for (int f = 0; f < FOUT; ++f) {
      float hv = S.hs[i][f];
      s0 = fmaf(hv, w1l[p][f], s0);
      s1 = fmaf(hv, w1l[p + 8][f], s1);
    }
    us[i][p] = fmaxf(s0, 0.0f);
    us[i][p + 8] = fmaxf(s1, 0.0f);
  }
  __syncthreads();
  if (t < 32) {
    float mu = b21[0], lv = b22[0];
#pragma unroll
    for (int k = 0; k < NH; ++k) {
      mu = fmaf(us[t][k], w21[k], mu);
      lv = fmaf(us[t][k], w22[k], lv);
    }
    float sp = fmaxf(lv, 0.0f) + log1pf(expf(-fabsf(lv)));
    float q = 0.5f * mu * mu - logf(sp);  // 0.5*log2pi terms cancel in qmp
#pragma unroll
    for (int off = 16; off; off >>= 1) q += __shfl_down(q, off);
    if (t == 0) qpart[blockIdx.x] = q;
  }
}

// ---------------- K2: attn, WAVE-AUTONOMOUS. 512 threads = 8 waves; wave w
// free-runs K-range [w*1024,(w+1)*1024) with NO barriers in the K-loop:
// the MFMA A-fragment (lane l -> adj[i0+(l&31)][k+(l>>5)*8..+7]) is loaded
// DIRECTLY from global as 2x dwordx4 and converted in-register, so no LDS
// staging / swizzle / lockstep is needed. 8 independent waves per CU hide
// HBM latency the way R0's 4 independent blocks did. Combine via LDS
// atomicAdd (64 ds_add/wave, 2-lanes-per-bank pattern), 1 barrier, fused
// deg-divide + ELU -> out. Block 0 reduces qpart.
__global__ __launch_bounds__(512, 2) void attn_kernel(
    const int* __restrict__ adj, const u16* __restrict__ HTf,
    const float* __restrict__ qpart, float* __restrict__ out) {
  __shared__ float accS[32 * FOUT];  // 16 KB
  __shared__ u32 degS[32];
  int t = threadIdx.x;
  int w = t >> 6, l = t & 63;
  int m = l & 31, kh = l >> 5;
  int i0 = blockIdx.x * 32;

  for (int e = t; e < 32 * FOUT; e += 512) accS[e] = 0.0f;
  if (t < 32) degS[t] = 0u;
  __syncthreads();

  int k0 = w * (NN / 8);  // 1024 adj cols per wave
  const int* ap = adj + (size_t)(i0 + m) * NN + k0 + kh * 8;
  const u16* bp = HTf + (size_t)(k0 >> 4) * 2048 + (size_t)l * 8;

  f32x16 acc[4];
#pragma unroll
  for (int nb = 0; nb < 4; ++nb)
#pragma unroll
    for (int r = 0; r < 16; ++r) acc[nb][r] = 0.0f;
  u32 degacc = 0;

  // Prologue: first iteration's A (K=32: two K16-steps, 8 ints each).
  int4 c0 = *(const int4*)(ap);
  int4 c1 = *(const int4*)(ap + 4);
  int4 c2 = *(const int4*)(ap + 16);
  int4 c3 = *(const int4*)(ap + 20);
  ap += 32;

  for (int it = 0; it < 32; ++it) {
    int4 n0, n1, n2, n3;
    if (it + 1 < 32) {  // depth-1 register prefetch of next K=32 chunk
      n0 = *(const int4*)(ap);
      n1 = *(const int4*)(ap + 4);
      n2 = *(const int4*)(ap + 16);
      n3 = *(const int4*)(ap + 20);
      ap += 32;
    }
    // K16-step 0: convert 8 ints {0,1} -> bf16x8, accumulate deg.
    {
      PackAB fa;
      u32 p0 = ((u32)c0.y << 16) | (u32)c0.x;
      u32 p1 = ((u32)c0.w << 16) | (u32)c0.z;
      u32 p2 = ((u32)c1.y << 16) | (u32)c1.x;
      u32 p3 = ((u32)c1.w << 16) | (u32)c1.z;
      degacc += p0 + p1 + p2 + p3;
      fa.u[0] = p0 * 0x3F80u; fa.u[1] = p1 * 0x3F80u;
      fa.u[2] = p2 * 0x3F80u; fa.u[3] = p3 * 0x3F80u;
#pragma unroll
      for (int nb = 0; nb < 4; ++nb) {
        bf16x8 bf = *(const bf16x8*)(bp + nb * 512);
        acc[nb] = __builtin_amdgcn_mfma_f32_32x32x16_bf16(fa.v, bf, acc[nb], 0, 0, 0);
      }
    }
    // K16-step 1.
    {
      PackAB fb;
      u32 p0 = ((u32)c2.y << 16) | (u32)c2.x;
      u32 p1 = ((u32)c2.w << 16) | (u32)c2.z;
      u32 p2 = ((u32)c3.y << 16) | (u32)c3.x;
      u32 p3 = ((u32)c3.w << 16) | (u32)c3.z;
      degacc += p0 + p1 + p2 + p3;
      fb.u[0] = p0 * 0x3F80u; fb.u[1] = p1 * 0x3F80u;
      fb.u[2] = p2 * 0x3F80u; fb.u[3] = p3 * 0x3F80u;
#pragma unroll
      for (int nb = 0; nb < 4; ++nb) {
        bf16x8 bf = *(const bf16x8*)(bp + 2048 + nb * 512);
        acc[nb] = __builtin_amdgcn_mfma_f32_32x32x16_bf16(fb.v, bf, acc[nb], 0, 0, 0);
      }
    }
    bp += 4096;
    c0 = n0; c1 = n1; c2 = n2; c3 = n3;
  }
  // Per-wave deg partial (two 16-bit halves, max 256 each: no overflow).
  {
    u32 d = (degacc & 0xFFFFu) + (degacc >> 16);
    atomicAdd(&degS[m], d);
  }
  // Combine accumulators across waves: 64 ds_add_f32 per wave.
  // Bank pattern per instr: lanes 0..31 -> words col 0..31 (banks 0..31),
  // lanes 32..63 -> same banks, different row = 2-way (free).
#pragma unroll
  for (int nb = 0; nb < 4; ++nb)
#pragma unroll
    for (int r = 0; r < 16; ++r) {
      int row = (r & 3) + 8 * (r >> 2) + 4 * kh;
      atomicAdd(&accS[row * 128 + nb * 32 + m], acc[nb][r]);
    }
  __syncthreads();
  // Fused deg-divide + ELU + store. 512 threads x 8 f32 = 32x128.
  {
    int idx = t * 8;
    int row = idx >> 7;
    float deg = (float)degS[row];
    float rd = deg != 0.0f ? 1.0f / deg : 0.0f;
    float4 v0 = *(const float4*)&accS[idx];
    float4 v1 = *(const float4*)&accS[idx + 4];
    float4 o0, o1;
    o0.x = v0.x * rd; o0.y = v0.y * rd; o0.z = v0.z * rd; o0.w = v0.w * rd;
    o1.x = v1.x * rd; o1.y = v1.y * rd; o1.z = v1.z * rd; o1.w = v1.w * rd;
    o0.x = o0.x > 0.0f ? o0.x : expm1f(o0.x);
    o0.y = o0.y > 0.0f ? o0.y : expm1f(o0.y);
    o0.z = o0.z > 0.0f ? o0.z : expm1f(o0.z);
    o0.w = o0.w > 0.0f ? o0.w : expm1f(o0.w);
    o1.x = o1.x > 0.0f ? o1.x : expm1f(o1.x);
    o1.y = o1.y > 0.0f ? o1.y : expm1f(o1.y);
    o1.z = o1.z > 0.0f ? o1.z : expm1f(o1.z);
    o1.w = o1.w > 0.0f ? o1.w : expm1f(o1.w);
    float* op = out + (size_t)(i0 + row) * FOUT + (idx & 127);
    *(float4*)op = o0;
    *(float4*)(op + 4) = o1;
  }
  if (blockIdx.x == 0 && t < 64) {  // qpart complete (prior dispatch)
    float v = qpart[t] + qpart[t + 64] + qpart[t + 128] + qpart[t + 192];
#pragma unroll
    for (int off = 32; off; off >>= 1) v += __shfl_down(v, off);
    if (t == 0) out[(size_t)NN * FOUT] = v;
  }
}

extern "C" void kernel_launch(void* const* d_in, const int* in_sizes, int n_in,
                              void* d_out, int out_size, void* d_ws, size_t ws_size,
                              hipStream_t stream) {
  (void)in_sizes; (void)n_in; (void)out_size; (void)ws_size;
  const float* x   = (const float*)d_in[0];
  const int*   adj = (const int*)d_in[1];
  const float* W   = (const float*)d_in[2];
  const float* w1  = (const float*)d_in[3];
  const float* b1  = (const float*)d_in[4];
  const float* w21 = (const float*)d_in[5];
  const float* b21 = (const float*)d_in[6];
  const float* w22 = (const float*)d_in[7];
  const float* b22 = (const float*)d_in[8];
  float* out = (float*)d_out;

  // Workspace: ~2.15 MB total.
  char* ws = (char*)d_ws;
  u16*   HTf  = (u16*)ws;   ws += (size_t)NN * FOUT * 2;   // 2 MB
  u16*   WT   = (u16*)ws;   ws += (size_t)FOUT * FIN * 2;  // 128 KB
  float* w1s  = (float*)ws; ws += NH * FOUT * 4;           // 8 KB
  float* qpart= (float*)ws;                                // 1 KB

  prep_kernel<<<257, 256, 0, stream>>>(W, w1, WT, w1s);
  h_fused_kernel<<<256, 256, 0, stream>>>(x, WT, b1, w21, b21, w22, b22, w1s, HTf, qpart);
  attn_kernel<<<256, 512, 0, stream>>>(adj, HTf, qpart, out);
}

// Round 5
// 432.732 us; speedup vs baseline: 1.1658x; 1.1658x over previous
//
#include <hip/hip_runtime.h>

typedef unsigned int u32;
typedef unsigned short u16;

#define NN 8192
#define FIN 512
#define FOUT 128
#define NH 16
#define BK 64    // h GEMM K-slab (u16 cols)
#define BKA 256  // attn K-slab (ints)

typedef float f32x16 __attribute__((ext_vector_type(16)));
typedef __bf16 bf16x8 __attribute__((ext_vector_type(8)));

union PackAB { u32 u[4]; bf16x8 v; };

__device__ __forceinline__ u32 rne_hi(u32 u) {
  return u + (0x7FFFu + ((u >> 16) & 1u));  // RNE bf16 in high half
}
__device__ __forceinline__ u16 f32_to_bf16(float f) {
  return (u16)(rne_hi(__float_as_uint(f)) >> 16);
}

// ---------------- K0: WT = bf16(W^T) [128][512]; w1s = folded w1.
__global__ __launch_bounds__(256) void prep_kernel(
    const float* __restrict__ W, const float* __restrict__ w1,
    u16* __restrict__ WT, float* __restrict__ w1s) {
  int b = blockIdx.x, t = threadIdx.x;
  if (b < 256) {
    int o = b * 256 + t;
    int n = o >> 9, k = o & 511;
    WT[o] = f32_to_bf16(W[k * FOUT + n]);
  } else {
    for (int e = t; e < NH * FOUT; e += 256) {
      int k = e >> 7, f = e & 127;
      w1s[e] = w1[k * 256 + f] + w1[k * 256 + 128 + f];
    }
  }
}

// ---------------- K1: fused h = x@W (full K=512 per 32-row tile),
// then HTf frag-order write + attn-net -> qpart, all from LDS.
// Proven pass in R1/R3 (~13-15 us incl. prep; replaces R0's h_kernel+reduceH
// and Hp's 32 MB round-trip).
__global__ __launch_bounds__(256) void h_fused_kernel(
    const float* __restrict__ x, const u16* __restrict__ WT,
    const float* __restrict__ b1, const float* __restrict__ w21,
    const float* __restrict__ b21, const float* __restrict__ w22,
    const float* __restrict__ b22, const float* __restrict__ w1s,
    u16* __restrict__ HTf, float* __restrict__ qpart) {
  __shared__ union {
    struct { u16 aS[32 * BK]; u16 bS[128 * BK]; } g;  // 20.0 KB
    float hs[32][FOUT + 4];                            // 16.5 KB
  } S;
  __shared__ float w1l[NH][FOUT + 4];
  __shared__ float us[32][NH + 1];
  int t = threadIdx.x;
  int w = t >> 6, l = t & 63;
  int m = l & 31, kh = l >> 5;
  int i0 = blockIdx.x * 32;

  int arow = t >> 4, acol = (t & 15) * 4;
  int ac = (t & 15) >> 1, ah = t & 1;
  int aoff0 = arow * BK + ((ac ^ (arow & 7)) << 3) + ah * 4;
  int aoff1 = (arow + 16) * BK + ((ac ^ ((arow + 16) & 7)) << 3) + ah * 4;
  const float* ap0 = x + (size_t)(i0 + arow) * FIN + acol;
  const float* ap1 = ap0 + (size_t)16 * FIN;
  int hr = t >> 3, hc = t & 7;
  const u16* bp0 = WT + (size_t)hr * FIN + hc * 8;
  int boff[4];
#pragma unroll
  for (int p = 0; p < 4; ++p) {
    int r = hr + 32 * p;
    boff[p] = r * BK + ((hc ^ (r & 7)) << 3);
  }
  int aro = m * BK, am7 = m & 7;
  int nB = w * 32 + m;
  int bro = nB * BK, bm7 = nB & 7;

  // Preload the entire 32x512 x-panel: 16 float4/thread = one 64 KB burst.
  float4 xa[8], xb[8];
#pragma unroll
  for (int o = 0; o < 8; ++o) {
    xa[o] = *(const float4*)(ap0 + o * BK);
    xb[o] = *(const float4*)(ap1 + o * BK);
  }
  uint4 hC[4], hN[4];
#pragma unroll
  for (int j = 0; j < 4; ++j) hC[j] = *(const uint4*)(bp0 + (size_t)(32 * j) * FIN);
  bp0 += BK;

  f32x16 acc;
#pragma unroll
  for (int r = 0; r < 16; ++r) acc[r] = 0.0f;

#pragma unroll
  for (int o = 0; o < 8; ++o) {
    if (o) __syncthreads();
    uint2 w0, w1v;
    w0.x = (rne_hi(__float_as_uint(xa[o].y)) & 0xFFFF0000u) | (rne_hi(__float_as_uint(xa[o].x)) >> 16);
    w0.y = (rne_hi(__float_as_uint(xa[o].w)) & 0xFFFF0000u) | (rne_hi(__float_as_uint(xa[o].z)) >> 16);
    w1v.x = (rne_hi(__float_as_uint(xb[o].y)) & 0xFFFF0000u) | (rne_hi(__float_as_uint(xb[o].x)) >> 16);
    w1v.y = (rne_hi(__float_as_uint(xb[o].w)) & 0xFFFF0000u) | (rne_hi(__float_as_uint(xb[o].z)) >> 16);
    *(uint2*)&S.g.aS[aoff0] = w0;
    *(uint2*)&S.g.aS[aoff1] = w1v;
#pragma unroll
    for (int j = 0; j < 4; ++j) *(uint4*)&S.g.bS[boff[j]] = hC[j];
    __syncthreads();
    if (o + 1 < 8) {
#pragma unroll
      for (int j = 0; j < 4; ++j) hN[j] = *(const uint4*)(bp0 + (size_t)(32 * j) * FIN);
      bp0 += BK;
    }
#pragma unroll
    for (int s = 0; s < BK; s += 16) {
      int cA = (s >> 3) + kh;
      PackAB pa, pb;
      pa.v = *(const bf16x8*)&S.g.aS[aro + ((cA ^ am7) << 3)];
      pb.v = *(const bf16x8*)&S.g.bS[bro + ((cA ^ bm7) << 3)];
      acc = __builtin_amdgcn_mfma_f32_32x32x16_bf16(pa.v, pb.v, acc, 0, 0, 0);
    }
    if (o + 1 < 8) {
#pragma unroll
      for (int j = 0; j < 4; ++j) hC[j] = hN[j];
    }
  }
  __syncthreads();  // last MFMA reads of aS/bS done before hs overwrite
  {
    int col = w * 32 + m;
#pragma unroll
    for (int r = 0; r < 16; ++r) {
      int row = (r & 3) + 8 * (r >> 2) + 4 * kh;
      S.hs[row][col] = acc[r];
    }
  }
  for (int e = t; e < NH * FOUT; e += 256) w1l[e >> 7][e & 127] = w1s[e];
  __syncthreads();
  // HTf in MFMA B-fragment order: idx = ((k16*4 + n/32)*64 + (kh*32 + n%32))*8 + k%8
  {
    int n = t & 127, g2 = t >> 7;
#pragma unroll
    for (int gg = 0; gg < 2; ++gg) {
      int g = g2 + 2 * gg;
      int k16 = (i0 >> 4) + (g >> 1), khh = g & 1;
      u32 p[4];
#pragma unroll
      for (int j = 0; j < 4; ++j) {
        u16 lo = f32_to_bf16(S.hs[g * 8 + 2 * j][n]);
        u16 hi = f32_to_bf16(S.hs[g * 8 + 2 * j + 1][n]);
        p[j] = (u32)lo | ((u32)hi << 16);
      }
      uint4 st; st.x = p[0]; st.y = p[1]; st.z = p[2]; st.w = p[3];
      size_t off = ((size_t)(k16 * 4 + (n >> 5)) * 64 + khh * 32 + (n & 31)) * 8;
      *(uint4*)(HTf + off) = st;
    }
  }
  {
    int i = t >> 3, p = t & 7;
    float s0 = b1[p], s1 = b1[p + 8];
#pragma unroll 4
    for (int f = 0; f < FOUT; ++f) {
      float hv = S.hs[i][f];
      s0 = fmaf(hv, w1l[p][f], s0);
      s1 = fmaf(hv, w1l[p + 8][f], s1);
    }
    us[i][p] = fmaxf(s0, 0.0f);
    us[i][p + 8] = fmaxf(s1, 0.0f);
  }
  __syncthreads();
  if (t < 32) {
    float mu = b21[0], lv = b22[0];
#pragma unroll
    for (int k = 0; k < NH; ++k) {
      mu = fmaf(us[t][k], w21[k], mu);
      lv = fmaf(us[t][k], w22[k], lv);
    }
    float sp = fmaxf(lv, 0.0f) + log1pf(expf(-fabsf(lv)));
    float q = 0.5f * mu * mu - logf(sp);  // 0.5*log2pi terms cancel in qmp
#pragma unroll
    for (int off = 16; off; off >>= 1) q += __shfl_down(q, off);
    if (t == 0) qpart[blockIdx.x] = q;
  }
}

// ---------------- K3: Sp[chunk] = adj-chunk @ h-chunk + deg partials.
// REVERTED to the R0 harness-proven structure: KSA split-K across blocks,
// 4 independent 4-wave blocks per CU (grid 256*KSA) hide HBM latency by
// being at different loop phases. A-only LDS staging with register
// prefetch of next slab; B frags direct from global HTf with 4-deep
// register double-buffer.
__global__ __launch_bounds__(256, 4) void attn_kernel(
    const int* __restrict__ adj, const u16* __restrict__ HTf,
    float* __restrict__ Sp, u32* __restrict__ degw, int KL) {
  __shared__ u16 aS[32 * BKA];  // 16 KB
  int t = threadIdx.x;
  int w = t >> 6, l = t & 63;
  int m = l & 31, kh = l >> 5;
  int tile = blockIdx.x & 255, chunk = blockIdx.x >> 8;
  int i0 = tile * 32, k0 = chunk * KL;

  int ar = t >> 3, lc = t & 7;
  const int* apb = adj + (size_t)(i0 + ar) * NN + k0 + lc * 4;
  int woff[8];
#pragma unroll
  for (int q = 0; q < 8; ++q) {
    int c = q * 4 + (lc >> 1);
    woff[q] = ar * 256 + (((c ^ ar) & 31) << 3) + (lc & 1) * 4;
  }
  const u16* bp = HTf + ((size_t)(k0 >> 4) * 4 * 64 + (size_t)(w * 64 + l)) * 8;

  f32x16 acc;
#pragma unroll
  for (int r = 0; r < 16; ++r) acc[r] = 0.0f;
  u32 degacc = 0;

  int nslab = KL / BKA;
  int4 aC[8], aN[8];
#pragma unroll
  for (int q = 0; q < 8; ++q) aC[q] = *(const int4*)(apb + q * 32);
  apb += BKA;

  for (int o = 0; o < nslab; ++o) {
    if (o) __syncthreads();  // previous slab's MFMA reads done
#pragma unroll
    for (int q = 0; q < 8; ++q) {
      u32 p0 = ((u32)aC[q].y << 16) | (u32)aC[q].x;
      u32 p1 = ((u32)aC[q].w << 16) | (u32)aC[q].z;
      degacc += p0 + p1;
      uint2 wv; wv.x = p0 * 0x3F80u; wv.y = p1 * 0x3F80u;  // {0,1} -> bf16
      *(uint2*)&aS[woff[q]] = wv;
    }
    __syncthreads();
    if (o + 1 < nslab) {  // prefetch next slab NOW; hides under MFMA phase
#pragma unroll
      for (int q = 0; q < 8; ++q) aN[q] = *(const int4*)(apb + q * 32);
      apb += BKA;
    }
    // MFMA phase: 16 steps, B 4-deep register double-buffer
    {
      bf16x8 bF[4];
#pragma unroll
      for (int j = 0; j < 4; ++j) bF[j] = *(const bf16x8*)(bp + j * 2048);
#pragma unroll
      for (int k16 = 0; k16 < 16; k16 += 4) {
        bf16x8 bN[4];
        if (k16 + 4 < 16) {
#pragma unroll
          for (int j = 0; j < 4; ++j)
            bN[j] = *(const bf16x8*)(bp + (k16 + 4 + j) * 2048);
        }
#pragma unroll
        for (int j = 0; j < 4; ++j) {
          int cc = (k16 + j) * 2 + kh;
          PackAB pa;
          pa.v = *(const bf16x8*)&aS[m * 256 + (((cc ^ m) & 31) << 3)];
          acc = __builtin_amdgcn_mfma_f32_32x32x16_bf16(pa.v, bF[j], acc, 0, 0, 0);
        }
#pragma unroll
        for (int j = 0; j < 4; ++j) bF[j] = bN[j];
      }
    }
    bp += (size_t)16 * 2048;
#pragma unroll
    for (int q = 0; q < 8; ++q) aC[q] = aN[q];
  }
  u32 d = (degacc & 0xFFFFu) + (degacc >> 16);
  d += __shfl_down(d, 4);
  d += __shfl_down(d, 2);
  d += __shfl_down(d, 1);
  if (lc == 0) degw[chunk * NN + i0 + ar] = d;
  float* sp = Sp + (size_t)chunk * NN * FOUT;
  int col = w * 32 + m;
#pragma unroll
  for (int r = 0; r < 16; ++r) {
    int row = (r & 3) + 8 * (r >> 2) + 4 * kh;
    sp[(size_t)(i0 + row) * FOUT + col] = acc[r];
  }
}

// ---------------- K4: blocks<1024: out = elu(sum(Sp)/deg); block 1024: qmp.
__global__ __launch_bounds__(256) void reduceSq_kernel(
    const float* __restrict__ Sp, const u32* __restrict__ degw,
    const float* __restrict__ qpart, float* __restrict__ out, int KSA) {
  int t = threadIdx.x;
  if (blockIdx.x == 1024) {
    __shared__ float sred[4];
    float v = qpart[t];
#pragma unroll
    for (int off = 32; off; off >>= 1) v += __shfl_down(v, off);
    if ((t & 63) == 0) sred[t >> 6] = v;
    __syncthreads();
    if (t == 0) out[(size_t)NN * FOUT] = sred[0] + sred[1] + sred[2] + sred[3];
    return;
  }
  int idx = (blockIdx.x * 256 + t) * 4;
  int i = idx >> 7;
  u32 deg = 0;
  for (int c = 0; c < KSA; ++c) deg += degw[c * NN + i];
  float4 s = {0.0f, 0.0f, 0.0f, 0.0f};
  for (int c = 0; c < KSA; ++c) {
    float4 v4 = *(const float4*)(Sp + (size_t)c * NN * FOUT + idx);
    s.x += v4.x; s.y += v4.y; s.z += v4.z; s.w += v4.w;
  }
  float rd = deg ? 1.0f / (float)deg : 0.0f;
  float4 o;
  o.x = s.x * rd; o.y = s.y * rd; o.z = s.z * rd; o.w = s.w * rd;
  o.x = o.x > 0.0f ? o.x : expm1f(o.x);
  o.y = o.y > 0.0f ? o.y : expm1f(o.y);
  o.z = o.z > 0.0f ? o.z : expm1f(o.z);
  o.w = o.w > 0.0f ? o.w : expm1f(o.w);
  *(float4*)(out + idx) = o;
}

extern "C" void kernel_launch(void* const* d_in, const int* in_sizes, int n_in,
                              void* d_out, int out_size, void* d_ws, size_t ws_size,
                              hipStream_t stream) {
  (void)in_sizes; (void)n_in; (void)out_size;
  const float* x   = (const float*)d_in[0];
  const int*   adj = (const int*)d_in[1];
  const float* W   = (const float*)d_in[2];
  const float* w1  = (const float*)d_in[3];
  const float* b1  = (const float*)d_in[4];
  const float* w21 = (const float*)d_in[5];
  const float* b21 = (const float*)d_in[6];
  const float* w22 = (const float*)d_in[7];
  const float* b22 = (const float*)d_in[8];
  float* out = (float*)d_out;

  const size_t TILE4 = (size_t)NN * FOUT * 4;  // 4 MB
  int KSA = 4;
  for (;;) {
    size_t need = (size_t)KSA * TILE4
                + (size_t)NN * FOUT * 2             // HTf
                + (size_t)FOUT * FIN * 2            // WT
                + (size_t)KSA * NN * 4              // degw
                + NH * FOUT * 4 + 2048;             // w1s + qpart
    if (need <= ws_size || KSA == 1) break;
    KSA >>= 1;
  }

  char* ws = (char*)d_ws;
  float* Sp   = (float*)ws;                          ws += (size_t)KSA * TILE4;
  u16*   HTf  = (u16*)ws;                            ws += (size_t)NN * FOUT * 2;
  u16*   WT   = (u16*)ws;                            ws += (size_t)FOUT * FIN * 2;
  u32*   degw = (u32*)ws;                            ws += (size_t)KSA * NN * 4;
  float* w1s  = (float*)ws;                          ws += NH * FOUT * 4;
  float* qpart= (float*)ws;

  prep_kernel<<<257, 256, 0, stream>>>(W, w1, WT, w1s);
  h_fused_kernel<<<256, 256, 0, stream>>>(x, WT, b1, w21, b21, w22, b22, w1s, HTf, qpart);
  attn_kernel<<<256 * KSA, 256, 0, stream>>>(adj, HTf, Sp, degw, NN / KSA);
  reduceSq_kernel<<<1025, 256, 0, stream>>>(Sp, degw, qpart, out, KSA);
}